// Round 1
// 582.453 us; speedup vs baseline: 1.4380x; 1.4380x over previous
//
#include <hip/hip_runtime.h>

// Workspace layout (floats), written by prep_kernel each call.
// All weights pre-transposed to column-major so the inner "broadcast h_j,
// FMA into a[0..31]" form reads contiguous wave-uniform columns (-> s_load).
// W_ih, (b_ih+b_hh), W_hh are pre-scaled by K = 2*log2(e) so that
// tanh(a) = 1 - 2/(1 + exp2(K*a)) needs no per-element scaling.
#define OFF_WIH 0      // 32   : W_ih[k]*K
#define OFF_C   32     // 32   : (b_ih[k]+b_hh[k])*K
#define OFF_WHH 64     // 1024 : col-major W_hh[k][j]*K at [j*32 + k]
#define OFF_W1  1088   // 1536 : col-major W1[o][m]    at [m*16 + o]
#define OFF_B1  2624   // 16
#define OFF_W2  2640   // 128  : col-major W2[o][k]    at [k*8 + o]
#define OFF_B2  2768   // 8
#define OFF_W3  2776   // 8
#define OFF_B3  2784   // 1

__global__ void prep_kernel(const float* __restrict__ wih, const float* __restrict__ whh,
                            const float* __restrict__ bih, const float* __restrict__ bhh,
                            const float* __restrict__ w1,  const float* __restrict__ b1,
                            const float* __restrict__ w2,  const float* __restrict__ b2,
                            const float* __restrict__ w3,  const float* __restrict__ b3,
                            float* __restrict__ ws)
{
    const float K = 2.8853900817779268f; // 2*log2(e)
    const int t = threadIdx.x;
    if (t < 32) {
        ws[OFF_WIH + t] = wih[t] * K;
        ws[OFF_C   + t] = (bih[t] + bhh[t]) * K;
    }
    for (int i = t; i < 1024; i += 256) {          // W_hh [32,32] row-major -> col-major, scaled
        int r = i >> 5, c = i & 31;                // whh[r][c]
        ws[OFF_WHH + c * 32 + r] = whh[i] * K;
    }
    for (int i = t; i < 1536; i += 256) {          // W1 [16,96] -> col-major
        int o = i / 96, m = i - o * 96;
        ws[OFF_W1 + m * 16 + o] = w1[i];
    }
    if (t < 16) ws[OFF_B1 + t] = b1[t];
    for (int i = t; i < 128; i += 256) {           // W2 [8,16] -> col-major
        int o = i >> 4, k = i & 15;
        ws[OFF_W2 + k * 8 + o] = w2[i];
    }
    if (t < 8) { ws[OFF_B2 + t] = b2[t]; ws[OFF_W3 + t] = w3[t]; }
    if (t == 0) ws[OFF_B3] = b3[0];
}

// tanh(a) given ap = 2*log2(e)*a:  tanh(a) = 1 - 2/(exp2(ap)+1)
__device__ __forceinline__ float tanh_fast(float ap) {
    float e = __builtin_amdgcn_exp2f(ap);
    return fmaf(-2.0f, __builtin_amdgcn_rcpf(e + 1.0f), 1.0f);
}

// __launch_bounds__(256, 1): min 1 wave/EU -> VGPR cap 512.
// Live state during the W_hh matvec is h[32]+a[32]+f1[16] = 80 floats; the
// previous build's 72-VGPR cap forced AGPR copy-spills (v_accvgpr_read/write
// = VALU traffic, invisible in WRITE_SIZE), inflating VALUBusy ~10x over the
// useful FMA count. Let the allocator keep everything in arch VGPRs.
__global__ __launch_bounds__(256, 1)
void rnn_mlp_kernel(const float* __restrict__ x, const float* __restrict__ ws,
                    float* __restrict__ out, int B)
{
    const int idx = blockIdx.x * 256 + threadIdx.x;
    // B is a multiple of 256 in this problem; clamp instead of early-return so
    // the (wave-uniform) weight loads sit in uniform control flow. Tail lanes,
    // if any, redundantly recompute element B-1 (benign same-value write).
    const int i = (idx < B) ? idx : (B - 1);

    const float x1 = x[3 * i + 0];
    const float x2 = x[3 * i + 1];
    const float x3 = x[3 * i + 2];

    float h[32];
    float a[32];
    float f1[16];

    #pragma unroll
    for (int o = 0; o < 16; ++o) f1[o] = ws[OFF_B1 + o];

    #pragma unroll
    for (int t = 0; t < 3; ++t) {
        const float xv = (t == 0) ? x1 : ((t == 1) ? x2 : x3);

        // pre-activation (scaled by K): a = xv*Wih' + c'  (+ Whh'*h for t>0)
        #pragma unroll
        for (int k = 0; k < 32; ++k) a[k] = fmaf(xv, ws[OFF_WIH + k], ws[OFF_C + k]);

        if (t > 0) {
            #pragma unroll
            for (int j = 0; j < 32; ++j) {
                const float hj = h[j];
                #pragma unroll
                for (int k = 0; k < 32; ++k)
                    a[k] = fmaf(hj, ws[OFF_WHH + j * 32 + k], a[k]);
            }
        }

        #pragma unroll
        for (int k = 0; k < 32; ++k) h[k] = tanh_fast(a[k]);

        // fc1 accumulation: f1[o] += relu(h[j]) * W1[o][t*32+j]
        #pragma unroll
        for (int j = 0; j < 32; ++j) {
            const float r = fmaxf(h[j], 0.0f);
            #pragma unroll
            for (int o = 0; o < 16; ++o)
                f1[o] = fmaf(r, ws[OFF_W1 + (t * 32 + j) * 16 + o], f1[o]);
        }
    }

    // fc2 (16 -> 8) + relu
    float g[8];
    #pragma unroll
    for (int o = 0; o < 8; ++o) g[o] = ws[OFF_B2 + o];
    #pragma unroll
    for (int k = 0; k < 16; ++k) {
        const float v = f1[k];
        #pragma unroll
        for (int o = 0; o < 8; ++o)
            g[o] = fmaf(v, ws[OFF_W2 + k * 8 + o], g[o]);
    }

    // fc3 (8 -> 1)
    float y = ws[OFF_B3];
    #pragma unroll
    for (int o = 0; o < 8; ++o)
        y = fmaf(fmaxf(g[o], 0.0f), ws[OFF_W3 + o], y);

    out[i] = y;
}

extern "C" void kernel_launch(void* const* d_in, const int* in_sizes, int n_in,
                              void* d_out, int out_size, void* d_ws, size_t ws_size,
                              hipStream_t stream)
{
    const float* x   = (const float*)d_in[0];
    const float* wih = (const float*)d_in[1];
    const float* whh = (const float*)d_in[2];
    const float* bih = (const float*)d_in[3];
    const float* bhh = (const float*)d_in[4];
    const float* w1  = (const float*)d_in[5];
    const float* b1  = (const float*)d_in[6];
    const float* w2  = (const float*)d_in[7];
    const float* b2  = (const float*)d_in[8];
    const float* w3  = (const float*)d_in[9];
    const float* b3  = (const float*)d_in[10];
    float* out = (float*)d_out;
    float* ws  = (float*)d_ws;

    const int B = in_sizes[0] / 3;

    prep_kernel<<<1, 256, 0, stream>>>(wih, whh, bih, bhh, w1, b1, w2, b2, w3, b3, ws);
    rnn_mlp_kernel<<<(B + 255) / 256, 256, 0, stream>>>(x, ws, out, B);
}

// Round 2
// 278.944 us; speedup vs baseline: 3.0026x; 2.0881x over previous
//
#include <hip/hip_runtime.h>

// Workspace layout (floats), written by prep_kernel each call.
// All weights pre-transposed to column-major so the inner "broadcast h_j,
// FMA into a[0..31]" form reads contiguous wave-uniform columns (-> s_load).
// W_ih, (b_ih+b_hh), W_hh are pre-scaled by K = 2*log2(e) so that
// tanh(a) = 1 - 2/(1 + exp2(K*a)) needs no per-element scaling.
#define OFF_WIH 0      // 32   : W_ih[k]*K
#define OFF_C   32     // 32   : (b_ih[k]+b_hh[k])*K
#define OFF_WHH 64     // 1024 : col-major W_hh[k][j]*K at [j*32 + k]
#define OFF_W1  1088   // 1536 : col-major W1[o][m]    at [m*16 + o]
#define OFF_B1  2624   // 16
#define OFF_W2  2640   // 128  : col-major W2[o][k]    at [k*8 + o]
#define OFF_B2  2768   // 8
#define OFF_W3  2776   // 8
#define OFF_B3  2784   // 1

__global__ void prep_kernel(const float* __restrict__ wih, const float* __restrict__ whh,
                            const float* __restrict__ bih, const float* __restrict__ bhh,
                            const float* __restrict__ w1,  const float* __restrict__ b1,
                            const float* __restrict__ w2,  const float* __restrict__ b2,
                            const float* __restrict__ w3,  const float* __restrict__ b3,
                            float* __restrict__ ws)
{
    const float K = 2.8853900817779268f; // 2*log2(e)
    const int t = threadIdx.x;
    if (t < 32) {
        ws[OFF_WIH + t] = wih[t] * K;
        ws[OFF_C   + t] = (bih[t] + bhh[t]) * K;
    }
    for (int i = t; i < 1024; i += 256) {          // W_hh [32,32] row-major -> col-major, scaled
        int r = i >> 5, c = i & 31;                // whh[r][c]
        ws[OFF_WHH + c * 32 + r] = whh[i] * K;
    }
    for (int i = t; i < 1536; i += 256) {          // W1 [16,96] -> col-major
        int o = i / 96, m = i - o * 96;
        ws[OFF_W1 + m * 16 + o] = w1[i];
    }
    if (t < 16) ws[OFF_B1 + t] = b1[t];
    for (int i = t; i < 128; i += 256) {           // W2 [8,16] -> col-major
        int o = i >> 4, k = i & 15;
        ws[OFF_W2 + k * 8 + o] = w2[i];
    }
    if (t < 8) { ws[OFF_B2 + t] = b2[t]; ws[OFF_W3 + t] = w3[t]; }
    if (t == 0) ws[OFF_B3] = b3[0];
}

// tanh(a) given ap = 2*log2(e)*a:  tanh(a) = 1 - 2/(exp2(ap)+1)
__device__ __forceinline__ float tanh_fast(float ap) {
    float e = __builtin_amdgcn_exp2f(ap);
    return fmaf(-2.0f, __builtin_amdgcn_rcpf(e + 1.0f), 1.0f);
}

// 2 batch elements per thread, paired (i, i+B/2) so both streams stay
// coalesced. Every wave-uniform weight s_load now feeds TWO fmas, halving
// the per-element weight-stream cost (s_load issue + latency chains), which
// R1's counters say dominates (VALUBusy ~94% yet 6.5x above the FMA floor).
// __launch_bounds__(256,2): cap 256 VGPR -> keep 2 waves/EU for SMEM latency
// hiding. Live state 2*(32+32+16)=160 floats; R1's allocator held 80 floats
// in 68 VGPRs, so ~160-200 VGPRs is expected to fit without spill.
__global__ __launch_bounds__(256, 2)
void rnn_mlp_kernel(const float* __restrict__ x, const float* __restrict__ ws,
                    float* __restrict__ out, int B)
{
    const int Bh  = (B + 1) >> 1;                  // elements per stream half
    const int idx = blockIdx.x * 256 + threadIdx.x;
    // Clamp instead of early-return: weight loads stay in uniform control
    // flow; tail threads duplicate a valid element (benign same-value write).
    const int i0 = (idx < Bh) ? idx : (Bh - 1);
    int i1 = i0 + Bh; if (i1 >= B) i1 = B - 1;

    float xa[2][3];
    #pragma unroll
    for (int t = 0; t < 3; ++t) {
        xa[0][t] = x[3 * i0 + t];
        xa[1][t] = x[3 * i1 + t];
    }

    float h[2][32];
    float a[2][32];
    float f1[2][16];

    #pragma unroll
    for (int o = 0; o < 16; ++o) {
        const float b = ws[OFF_B1 + o];
        f1[0][o] = b; f1[1][o] = b;
    }

    #pragma unroll
    for (int t = 0; t < 3; ++t) {
        const float xv0 = xa[0][t];
        const float xv1 = xa[1][t];

        // pre-activation (scaled by K): a = xv*Wih' + c'  (+ Whh'*h for t>0)
        #pragma unroll
        for (int k = 0; k < 32; ++k) {
            const float w = ws[OFF_WIH + k];
            const float c = ws[OFF_C + k];
            a[0][k] = fmaf(xv0, w, c);
            a[1][k] = fmaf(xv1, w, c);
        }

        if (t > 0) {
            #pragma unroll
            for (int j = 0; j < 32; ++j) {
                const float hj0 = h[0][j];
                const float hj1 = h[1][j];
                #pragma unroll
                for (int k = 0; k < 32; ++k) {
                    const float w = ws[OFF_WHH + j * 32 + k];
                    a[0][k] = fmaf(hj0, w, a[0][k]);
                    a[1][k] = fmaf(hj1, w, a[1][k]);
                }
            }
        }

        #pragma unroll
        for (int k = 0; k < 32; ++k) {
            h[0][k] = tanh_fast(a[0][k]);
            h[1][k] = tanh_fast(a[1][k]);
        }

        // fc1 accumulation: f1[o] += relu(h[j]) * W1[o][t*32+j]
        #pragma unroll
        for (int j = 0; j < 32; ++j) {
            const float r0 = fmaxf(h[0][j], 0.0f);
            const float r1 = fmaxf(h[1][j], 0.0f);
            #pragma unroll
            for (int o = 0; o < 16; ++o) {
                const float w = ws[OFF_W1 + (t * 32 + j) * 16 + o];
                f1[0][o] = fmaf(r0, w, f1[0][o]);
                f1[1][o] = fmaf(r1, w, f1[1][o]);
            }
        }
    }

    // fc2 (16 -> 8) + relu
    float g[2][8];
    #pragma unroll
    for (int o = 0; o < 8; ++o) {
        const float b = ws[OFF_B2 + o];
        g[0][o] = b; g[1][o] = b;
    }
    #pragma unroll
    for (int k = 0; k < 16; ++k) {
        const float v0 = f1[0][k];
        const float v1 = f1[1][k];
        #pragma unroll
        for (int o = 0; o < 8; ++o) {
            const float w = ws[OFF_W2 + k * 8 + o];
            g[0][o] = fmaf(v0, w, g[0][o]);
            g[1][o] = fmaf(v1, w, g[1][o]);
        }
    }

    // fc3 (8 -> 1)
    float y0 = ws[OFF_B3];
    float y1 = y0;
    #pragma unroll
    for (int o = 0; o < 8; ++o) {
        const float w = ws[OFF_W3 + o];
        y0 = fmaf(fmaxf(g[0][o], 0.0f), w, y0);
        y1 = fmaf(fmaxf(g[1][o], 0.0f), w, y1);
    }

    out[i0] = y0;
    out[i1] = y1;
}

extern "C" void kernel_launch(void* const* d_in, const int* in_sizes, int n_in,
                              void* d_out, int out_size, void* d_ws, size_t ws_size,
                              hipStream_t stream)
{
    const float* x   = (const float*)d_in[0];
    const float* wih = (const float*)d_in[1];
    const float* whh = (const float*)d_in[2];
    const float* bih = (const float*)d_in[3];
    const float* bhh = (const float*)d_in[4];
    const float* w1  = (const float*)d_in[5];
    const float* b1  = (const float*)d_in[6];
    const float* w2  = (const float*)d_in[7];
    const float* b2  = (const float*)d_in[8];
    const float* w3  = (const float*)d_in[9];
    const float* b3  = (const float*)d_in[10];
    float* out = (float*)d_out;
    float* ws  = (float*)d_ws;

    const int B = in_sizes[0] / 3;

    prep_kernel<<<1, 256, 0, stream>>>(wih, whh, bih, bhh, w1, b1, w2, b2, w3, b3, ws);
    const int Bh = (B + 1) >> 1;
    rnn_mlp_kernel<<<(Bh + 255) / 256, 256, 0, stream>>>(x, ws, out, B);
}